// Round 1
// 734.265 us; speedup vs baseline: 1.0628x; 1.0628x over previous
//
#include <hip/hip_runtime.h>
#include <math.h>

#define NB 32
#define NN 3136
#define CD 320
#define NH 5
#define CN 400
#define NKEY 196
#define DQ 80
#define DV 64
#define SCALE_F 0.11180339887498949f

typedef __bf16 bf16x8 __attribute__((ext_vector_type(8)));
typedef float f32x4 __attribute__((ext_vector_type(4)));
typedef unsigned short u16;
typedef unsigned int u32;

__device__ __forceinline__ u16 f2bf(float f) {
  u32 u = __float_as_uint(f);
  u += 0x7fffu + ((u >> 16) & 1u);  // round-to-nearest-even
  return (u16)(u >> 16);
}

__device__ __forceinline__ bf16x8 pack8(const float4 a, const float4 b) {
  union { bf16x8 v; u16 s[8]; } u;
  u.s[0] = f2bf(a.x); u.s[1] = f2bf(a.y); u.s[2] = f2bf(a.z); u.s[3] = f2bf(a.w);
  u.s[4] = f2bf(b.x); u.s[5] = f2bf(b.y); u.s[6] = f2bf(b.z); u.s[7] = f2bf(b.w);
  return u.v;
}

// ---------------------------------------------------------------------------
// Prep: qwT bf16 [400][320]; pwT bf16 [320][320]; kvwT bf16 [720][416]
// (rows 0..399 = k_w^T, rows 400..719 = v_w^T, cols 400..415 zero).
// ---------------------------------------------------------------------------
__global__ void k_prep(const float* __restrict__ q_w,
                       const float* __restrict__ proj_w,
                       const float* __restrict__ k_w,
                       const float* __restrict__ v_w, u16* __restrict__ qwT,
                       u16* __restrict__ pwT, u16* __restrict__ kvwT) {
  const int i0 = blockIdx.x * 256 + threadIdx.x;
  const int stride = gridDim.x * 256;
  for (int idx = i0; idx < 400 * 320; idx += stride) {
    const int o = idx / 320, c = idx - o * 320;
    qwT[idx] = f2bf(q_w[(size_t)c * 400 + o]);
  }
  for (int idx = i0; idx < 320 * 320; idx += stride) {
    const int o = idx / 320, c = idx - o * 320;
    pwT[idx] = f2bf(proj_w[(size_t)c * 320 + o]);
  }
  for (int idx = i0; idx < 720 * 416; idx += stride) {
    const int o = idx / 416, c = idx - o * 416;
    float v = 0.f;
    if (c < 400) v = (o < 400) ? k_w[(size_t)c * 400 + o] : v_w[(size_t)c * 320 + (o - 400)];
    kvwT[idx] = f2bf(v);
  }
}

// ---------------------------------------------------------------------------
// Kernel 1: dwconv + 1x1 conv + LN + GELU -> xs bf16 [6272][416] (pad zeroed)
// ---------------------------------------------------------------------------
__global__ __launch_bounds__(256) void k_spatial(
    const float* __restrict__ x, const float* __restrict__ dw_w,
    const float* __restrict__ dw_b, const float* __restrict__ pw_w,
    const float* __restrict__ pw_b, const float* __restrict__ ln_g,
    const float* __restrict__ ln_b, u16* __restrict__ xs) {
  const int oh = blockIdx.x, b = blockIdx.y, tid = threadIdx.x;
  __shared__ float dwc[14][321];
  __shared__ float pre[14][401];
  const float* xb = x + (size_t)b * NN * CD;

  for (int idx = tid; idx < 14 * 320; idx += 256) {
    const int p = idx / 320, c = idx - p * 320;
    float acc = dw_b[c];
#pragma unroll
    for (int i = 0; i < 4; i++) {
#pragma unroll
      for (int j = 0; j < 4; j++) {
        const int pix = (oh * 4 + i) * 56 + p * 4 + j;
        acc += xb[(size_t)pix * CD + c] * dw_w[c * 16 + i * 4 + j];
      }
    }
    dwc[p][c] = acc;
  }
  __syncthreads();

  for (int o = tid; o < 400; o += 256) {
    float acc[14];
    const float bias = pw_b[o];
#pragma unroll
    for (int p = 0; p < 14; p++) acc[p] = bias;
    const float* wrow = pw_w + (size_t)o * 320;
    for (int c = 0; c < 320; c++) {
      const float w = wrow[c];
#pragma unroll
      for (int p = 0; p < 14; p++) acc[p] += dwc[p][c] * w;
    }
#pragma unroll
    for (int p = 0; p < 14; p++) pre[p][o] = acc[p];
  }
  __syncthreads();

  const int wave = tid >> 6, lane = tid & 63;
  for (int p = wave; p < 14; p += 4) {
    float s = 0.f, ss = 0.f;
    for (int o = lane; o < 400; o += 64) {
      const float v = pre[p][o];
      s += v;
      ss += v * v;
    }
#pragma unroll
    for (int off = 32; off > 0; off >>= 1) {
      s += __shfl_xor(s, off);
      ss += __shfl_xor(ss, off);
    }
    const float mu = s * (1.f / 400.f);
    const float var = ss * (1.f / 400.f) - mu * mu;
    const float rstd = rsqrtf(var + 1e-5f);
    u16* orow = xs + (size_t)(b * NKEY + oh * 14 + p) * 416;
    for (int o = lane; o < 400; o += 64) {
      const float v = (pre[p][o] - mu) * rstd * ln_g[o] + ln_b[o];
      orow[o] = f2bf(0.5f * v * (1.f + erff(v * 0.70710678118654752f)));
    }
    if (lane < 16) orow[400 + lane] = 0;
  }
}

// ---------------------------------------------------------------------------
// Kernel 2 (MFMA, barrier-free): [6272][416]bf16 @ kvwT^T -> kb [6272][400],
// vt [32][320][224] (v transposed, keys 196..223 left as poison — harmless).
// grid (98, 3): wave = 16 rows, N-chunk = 15 tiles of 16.
// ---------------------------------------------------------------------------
__global__ __launch_bounds__(256) void k_kv(const u16* __restrict__ xs,
                                            const u16* __restrict__ kvwT,
                                            u16* __restrict__ kb,
                                            u16* __restrict__ vt) {
  const int tid = threadIdx.x, lane = tid & 63, wv = tid >> 6;
  const int quad = lane >> 4, l15 = lane & 15;
  const int mt = blockIdx.x * 4 + wv;  // 0..391
  const f32x4 fz = {0.f, 0.f, 0.f, 0.f};

  bf16x8 A[13];
  {
    const u16* xr = xs + (size_t)(mt * 16 + l15) * 416;
#pragma unroll
    for (int ks = 0; ks < 13; ks++)
      A[ks] = *(const bf16x8*)(xr + ks * 32 + quad * 8);
  }
#pragma unroll 1
  for (int n = 0; n < 15; n++) {
    const int nt = blockIdx.y * 15 + n;
    f32x4 acc = fz;
    const u16* wr = kvwT + (size_t)(nt * 16 + l15) * 416;
#pragma unroll
    for (int ks = 0; ks < 13; ks++) {
      const bf16x8 B = *(const bf16x8*)(wr + ks * 32 + quad * 8);
      acc = __builtin_amdgcn_mfma_f32_16x16x32_bf16(A[ks], B, acc, 0, 0, 0);
    }
    const int col = nt * 16 + l15;
    if (col < 400) {
#pragma unroll
      for (int r = 0; r < 4; r++)
        kb[(size_t)(mt * 16 + quad * 4 + r) * 400 + col] = f2bf(acc[r]);
    } else {
      const int vo = col - 400;
#pragma unroll
      for (int r = 0; r < 4; r++) {
        const int row = mt * 16 + quad * 4 + r;
        const int bb = row / 196, key = row - bb * 196;
        vt[((size_t)(bb * 320 + vo)) * 224 + key] = f2bf(acc[r]);
      }
    }
  }
}

// ---------------------------------------------------------------------------
// Kernel 3 (MFMA, LDS-free, barrier-free): qb = x @ q_w  bf16 [100352][400].
// grid 784: 4 waves x 32 rows. A held in regs (x fp32 -> bf16 in-reg).
// ---------------------------------------------------------------------------
__global__ __launch_bounds__(256) void k_q(const float* __restrict__ x,
                                           const u16* __restrict__ qwT,
                                           u16* __restrict__ qb) {
  const int tid = threadIdx.x, lane = tid & 63, wv = tid >> 6;
  const int quad = lane >> 4, l15 = lane & 15;
  const int r0 = (blockIdx.x * 4 + wv) * 32;
  const f32x4 fz = {0.f, 0.f, 0.f, 0.f};

  bf16x8 A[2][10];
#pragma unroll
  for (int t = 0; t < 2; t++) {
    const float* xr = x + (size_t)(r0 + t * 16 + l15) * CD;
#pragma unroll
    for (int ks = 0; ks < 10; ks++) {
      const float4 a = *(const float4*)(xr + ks * 32 + quad * 8);
      const float4 b = *(const float4*)(xr + ks * 32 + quad * 8 + 4);
      A[t][ks] = pack8(a, b);
    }
  }
#pragma unroll 1
  for (int n = 0; n < 25; n++) {
    f32x4 acc[2] = {fz, fz};
    const u16* wr = qwT + (size_t)(n * 16 + l15) * CD;
#pragma unroll
    for (int ks = 0; ks < 10; ks++) {
      const bf16x8 B = *(const bf16x8*)(wr + ks * 32 + quad * 8);
      acc[0] = __builtin_amdgcn_mfma_f32_16x16x32_bf16(A[0][ks], B, acc[0], 0, 0, 0);
      acc[1] = __builtin_amdgcn_mfma_f32_16x16x32_bf16(A[1][ks], B, acc[1], 0, 0, 0);
    }
#pragma unroll
    for (int t = 0; t < 2; t++)
#pragma unroll
      for (int r = 0; r < 4; r++)
        qb[(size_t)(r0 + t * 16 + quad * 4 + r) * CN + n * 16 + l15] =
            f2bf(acc[t][r]);
  }
}

// ---------------------------------------------------------------------------
// Kernel 4: attention. grid (5, 49, 32), 2 barriers total.
// LDS 36624 B (-> 4 blocks/CU): Ks [208][88] (K=80 exact, cols 80..87 + rows
// 196..207 zeroed); P (wave-private [16][232]) overlays dead Ks.
// S-GEMM runs K=96 via 3x mfma16x16x32 with A zeroed for k>=80 (quads 2,3 of
// third tile); B cross-row overread (cols 88..95 -> next row cols 0..7) is
// finite and multiplied by A-zeros.
// Output: bf16 attn-out written IN PLACE into qb (this block's rows, cols
// h*80+0..63). Safe: this block is the sole reader of those (row,col) bytes
// and its last q read precedes the write. k_proj reads it; fp32 out roundtrip
// eliminated.
// ---------------------------------------------------------------------------
__global__ __launch_bounds__(256) void k_attn(u16* __restrict__ qb,
                                              const u16* __restrict__ kb,
                                              const u16* __restrict__ vt) {
  const int h = blockIdx.x, qt = blockIdx.y, b = blockIdx.z;
  const int tid = threadIdx.x, lane = tid & 63, wv = tid >> 6;
  const int quad = lane >> 4, l15 = lane & 15;
  const int q0 = qt * 64, m0 = wv * 16;
  const f32x4 fz = {0.f, 0.f, 0.f, 0.f};

  __shared__ u16 sm[208 * 88 + 8];  // 36624 B
  u16* Ks = sm;
  u16* P = sm + wv * (16 * 232);  // valid only after barrier #2

  // stage K head-slice: [196][80] -> Ks[196][88], cols 80..87 zeroed
  for (int idx = tid; idx < 196 * 11; idx += 256) {
    const int key = idx / 11, g = idx - key * 11;
    if (g < 10)
      *(uint4*)(Ks + key * 88 + g * 8) = *(const uint4*)(
          kb + ((size_t)(b * NKEY + key)) * CN + h * DQ + g * 8);
    else
      *(uint4*)(Ks + key * 88 + 80) = make_uint4(0, 0, 0, 0);
  }
  // zero rows 196..207 + 8-u16 tail guard (keeps the K96 overread finite)
  for (int idx = tid; idx < 12 * 11 + 1; idx += 256) {
    const int rr = idx / 11, g = idx - rr * 11;
    *(uint4*)(Ks + (196 + rr) * 88 + g * 8) = make_uint4(0, 0, 0, 0);
  }
  __syncthreads();  // barrier #1

  // ---- S = q @ K^T  (13 key-tiles; K=80 exact, A zero-padded to 96)
  f32x4 sacc[13];
#pragma unroll
  for (int n = 0; n < 13; n++) sacc[n] = fz;
  {
    const u16* qr = qb + (size_t)(b * NN + q0 + m0 + l15) * CN + h * DQ;
    bf16x8 a[3];
    a[0] = *(const bf16x8*)(qr + quad * 8);
    a[1] = *(const bf16x8*)(qr + 32 + quad * 8);
    if (quad < 2) {
      a[2] = *(const bf16x8*)(qr + 64 + quad * 8);
    } else {
      union { uint4 u; bf16x8 v; } z;
      z.u = make_uint4(0, 0, 0, 0);
      a[2] = z.v;
    }
#pragma unroll
    for (int n = 0; n < 13; n++)
#pragma unroll
      for (int ks = 0; ks < 3; ks++) {
        const bf16x8 B =
            *(const bf16x8*)(Ks + (n * 16 + l15) * 88 + ks * 32 + quad * 8);
        sacc[n] = __builtin_amdgcn_mfma_f32_16x16x32_bf16(a[ks], B, sacc[n], 0, 0, 0);
      }
  }

  // ---- softmax in registers (keys across 13 regs x 16 lanes)
  {
    float mx[4] = {-1e30f, -1e30f, -1e30f, -1e30f};
#pragma unroll
    for (int n = 0; n < 13; n++)
#pragma unroll
      for (int r = 0; r < 4; r++) {
        const float s = (n == 12 && l15 >= 4) ? -1e30f : sacc[n][r] * SCALE_F;
        sacc[n][r] = s;
        mx[r] = fmaxf(mx[r], s);
      }
#pragma unroll
    for (int r = 0; r < 4; r++) {
      mx[r] = fmaxf(mx[r], __shfl_xor(mx[r], 1));
      mx[r] = fmaxf(mx[r], __shfl_xor(mx[r], 2));
      mx[r] = fmaxf(mx[r], __shfl_xor(mx[r], 4));
      mx[r] = fmaxf(mx[r], __shfl_xor(mx[r], 8));
    }
    float sum[4] = {0.f, 0.f, 0.f, 0.f};
#pragma unroll
    for (int n = 0; n < 13; n++)
#pragma unroll
      for (int r = 0; r < 4; r++) {
        const float e = __expf(sacc[n][r] - mx[r]);
        sacc[n][r] = e;
        sum[r] += e;
      }
#pragma unroll
    for (int r = 0; r < 4; r++) {
      sum[r] += __shfl_xor(sum[r], 1);
      sum[r] += __shfl_xor(sum[r], 2);
      sum[r] += __shfl_xor(sum[r], 4);
      sum[r] += __shfl_xor(sum[r], 8);
    }
#pragma unroll
    for (int r = 0; r < 4; r++) {
      const float inv = 1.f / sum[r];
#pragma unroll
      for (int n = 0; n < 13; n++) sacc[n][r] *= inv;
    }
  }
  __syncthreads();  // barrier #2: Ks dead, P region live

  // ---- P -> wave-private LDS [16][232] (cols 196..223 zeroed)
  {
    const int zr = lane >> 2, zc0 = 196 + (lane & 3) * 7;
#pragma unroll
    for (int t = 0; t < 7; t++) P[zr * 232 + zc0 + t] = 0;
#pragma unroll
    for (int n = 0; n < 13; n++) {
      if (n == 12 && l15 >= 4) continue;
#pragma unroll
      for (int r = 0; r < 4; r++)
        P[(quad * 4 + r) * 232 + n * 16 + l15] = f2bf(sacc[n][r]);
    }
  }

  // ---- O = P @ V   (V B-frags direct from global vt [b*320+vo][224])
  f32x4 oacc[4];
#pragma unroll
  for (int n = 0; n < 4; n++) oacc[n] = fz;
  {
    const u16* vbase = vt + (size_t)(b * 320 + h * DV) * 224;
#pragma unroll
    for (int kk = 0; kk < 7; kk++) {
      const bf16x8 a = *(const bf16x8*)(P + l15 * 232 + kk * 32 + quad * 8);
#pragma unroll
      for (int n = 0; n < 4; n++) {
        const bf16x8 B = *(const bf16x8*)(vbase + (size_t)(n * 16 + l15) * 224 +
                                          kk * 32 + quad * 8);
        oacc[n] = __builtin_amdgcn_mfma_f32_16x16x32_bf16(a, B, oacc[n], 0, 0, 0);
      }
    }
  }
  // ---- bf16 attn-out overlay into qb (own rows, cols h*80+0..63)
#pragma unroll
  for (int n = 0; n < 4; n++)
#pragma unroll
    for (int r = 0; r < 4; r++)
      qb[(size_t)(b * NN + q0 + m0 + quad * 4 + r) * CN + h * DQ + n * 16 +
         l15] = f2bf(oacc[n][r]);
}

// ---------------------------------------------------------------------------
// Kernel 5 (LDS-free, barrier-free): out = ao @ proj_w + proj_b.
// ao = bf16 attn-out overlaid in qb: row stride 400, head h at cols h*80+0..63.
// A-frag col c = ks*32+quad*8+i  ->  addr row*400 + (ks>>1)*80 + (ks&1)*32 + quad*8.
// grid 784: wave = 32 rows. No pack needed (A already bf16).
// ---------------------------------------------------------------------------
__global__ __launch_bounds__(256) void k_proj(const u16* __restrict__ ao,
                                              const u16* __restrict__ pwT,
                                              const float* __restrict__ proj_b,
                                              float* __restrict__ out) {
  const int tid = threadIdx.x, lane = tid & 63, wv = tid >> 6;
  const int quad = lane >> 4, l15 = lane & 15;
  const int r0 = (blockIdx.x * 4 + wv) * 32;
  const f32x4 fz = {0.f, 0.f, 0.f, 0.f};

  bf16x8 A[2][10];
#pragma unroll
  for (int t = 0; t < 2; t++) {
    const u16* xr = ao + (size_t)(r0 + t * 16 + l15) * CN;
#pragma unroll
    for (int ks = 0; ks < 10; ks++)
      A[t][ks] = *(const bf16x8*)(xr + (ks >> 1) * DQ + (ks & 1) * 32 + quad * 8);
  }
#pragma unroll 1
  for (int n = 0; n < 20; n++) {
    f32x4 acc[2] = {fz, fz};
    const u16* wr = pwT + (size_t)(n * 16 + l15) * CD;
#pragma unroll
    for (int ks = 0; ks < 10; ks++) {
      const bf16x8 B = *(const bf16x8*)(wr + ks * 32 + quad * 8);
      acc[0] = __builtin_amdgcn_mfma_f32_16x16x32_bf16(A[0][ks], B, acc[0], 0, 0, 0);
      acc[1] = __builtin_amdgcn_mfma_f32_16x16x32_bf16(A[1][ks], B, acc[1], 0, 0, 0);
    }
    const float pb = proj_b[n * 16 + l15];
#pragma unroll
    for (int t = 0; t < 2; t++)
#pragma unroll
      for (int r = 0; r < 4; r++)
        out[(size_t)(r0 + t * 16 + quad * 4 + r) * CD + n * 16 + l15] =
            acc[t][r] + pb;
  }
}

// ---------------------------------------------------------------------------
extern "C" void kernel_launch(void* const* d_in, const int* in_sizes, int n_in,
                              void* d_out, int out_size, void* d_ws,
                              size_t ws_size, hipStream_t stream) {
  const float* x = (const float*)d_in[0];
  const float* dw_w = (const float*)d_in[3];
  const float* dw_b = (const float*)d_in[4];
  const float* pw_w = (const float*)d_in[5];
  const float* pw_b = (const float*)d_in[6];
  const float* ln_g = (const float*)d_in[7];
  const float* ln_b = (const float*)d_in[8];
  const float* q_w = (const float*)d_in[9];
  const float* k_w = (const float*)d_in[10];
  const float* v_w = (const float*)d_in[11];
  const float* proj_w = (const float*)d_in[12];
  const float* proj_b = (const float*)d_in[13];
  float* out = (float*)d_out;

  u16* w = (u16*)d_ws;
  u16* xs16 = w;                    // [6272][416]       = 2,609,152
  u16* kb16 = xs16 + 2609152;       // [6272][400]       = 2,508,800
  u16* vt16 = kb16 + 2508800;       // [32*320][224]     = 2,293,760
  u16* qb16 = vt16 + 2293760;       // [100352][400]+64  = 40,140,864 (ao overlay)
  u16* qwT = qb16 + 40140864;       // [400][320]        = 128,000
  u16* pwT = qwT + 128000;          // [320][320]        = 102,400
  u16* kvwT = pwT + 102400;         // [720][416]        = 299,520
                                    // total 96.2 MB

  k_prep<<<512, 256, 0, stream>>>(q_w, proj_w, k_w, v_w, qwT, pwT, kvwT);
  k_spatial<<<dim3(14, 32), 256, 0, stream>>>(x, dw_w, dw_b, pw_w, pw_b, ln_g,
                                              ln_b, xs16);
  k_kv<<<dim3(98, 3), 256, 0, stream>>>(xs16, kvwT, kb16, vt16);
  k_q<<<784, 256, 0, stream>>>(x, qwT, qb16);
  k_attn<<<dim3(NH, 49, NB), 256, 0, stream>>>(qb16, kb16, vt16);
  k_proj<<<784, 256, 0, stream>>>(qb16, pwT, proj_b, out);
}

// Round 2
// 723.739 us; speedup vs baseline: 1.0782x; 1.0145x over previous
//
#include <hip/hip_runtime.h>
#include <math.h>

#define NB 32
#define NN 3136
#define CD 320
#define NH 5
#define CN 400
#define NKEY 196
#define DQ 80
#define DV 64
#define SCALE_F 0.11180339887498949f

typedef __bf16 bf16x8 __attribute__((ext_vector_type(8)));
typedef float f32x4 __attribute__((ext_vector_type(4)));
typedef unsigned short u16;
typedef unsigned int u32;

__device__ __forceinline__ u16 f2bf(float f) {
  u32 u = __float_as_uint(f);
  u += 0x7fffu + ((u >> 16) & 1u);  // round-to-nearest-even
  return (u16)(u >> 16);
}

__device__ __forceinline__ bf16x8 pack8(const float4 a, const float4 b) {
  union { bf16x8 v; u16 s[8]; } u;
  u.s[0] = f2bf(a.x); u.s[1] = f2bf(a.y); u.s[2] = f2bf(a.z); u.s[3] = f2bf(a.w);
  u.s[4] = f2bf(b.x); u.s[5] = f2bf(b.y); u.s[6] = f2bf(b.z); u.s[7] = f2bf(b.w);
  return u.v;
}

// ---------------------------------------------------------------------------
// Prep: qwT bf16 [400][320]; pwT bf16 [320][320]; kvwT bf16 [720][416]
// (rows 0..399 = k_w^T, rows 400..719 = v_w^T, cols 400..415 zero);
// pwb bf16 [400][320] = pw_w cast (native out-major layout, no transpose).
// ---------------------------------------------------------------------------
__global__ void k_prep(const float* __restrict__ q_w,
                       const float* __restrict__ proj_w,
                       const float* __restrict__ k_w,
                       const float* __restrict__ v_w,
                       const float* __restrict__ pw_w, u16* __restrict__ qwT,
                       u16* __restrict__ pwT, u16* __restrict__ kvwT,
                       u16* __restrict__ pwb) {
  const int i0 = blockIdx.x * 256 + threadIdx.x;
  const int stride = gridDim.x * 256;
  for (int idx = i0; idx < 400 * 320; idx += stride) {
    const int o = idx / 320, c = idx - o * 320;
    qwT[idx] = f2bf(q_w[(size_t)c * 400 + o]);
  }
  for (int idx = i0; idx < 320 * 320; idx += stride) {
    const int o = idx / 320, c = idx - o * 320;
    pwT[idx] = f2bf(proj_w[(size_t)c * 320 + o]);
  }
  for (int idx = i0; idx < 400 * 320; idx += stride) {
    pwb[idx] = f2bf(pw_w[idx]);
  }
  for (int idx = i0; idx < 720 * 416; idx += stride) {
    const int o = idx / 416, c = idx - o * 416;
    float v = 0.f;
    if (c < 400) v = (o < 400) ? k_w[(size_t)c * 400 + o] : v_w[(size_t)c * 320 + (o - 400)];
    kvwT[idx] = f2bf(v);
  }
}

// ---------------------------------------------------------------------------
// Kernel 1a: depthwise 4x4/s4 conv, pure streaming. Thread = 4 channels of one
// output pixel. dwc fp32 [6272][320]. Reads x exactly once (128 MB).
// grid 1960 (= 6272*80/256).
// ---------------------------------------------------------------------------
__global__ __launch_bounds__(256) void k_dw(const float* __restrict__ x,
                                            const float* __restrict__ dw_w,
                                            const float* __restrict__ dw_b,
                                            float* __restrict__ dwc) {
  const int idx = blockIdx.x * 256 + threadIdx.x;  // 6272*80
  const int row = idx / 80, c4 = (idx - row * 80) * 4;
  const int b = row / 196, pl = row - b * 196;
  const int oh = pl / 14, ow = pl - oh * 14;
  const float* xb =
      x + ((size_t)b * NN + (size_t)(oh * 4) * 56 + ow * 4) * CD + c4;
  float a0 = dw_b[c4], a1 = dw_b[c4 + 1], a2 = dw_b[c4 + 2], a3 = dw_b[c4 + 3];
#pragma unroll
  for (int i = 0; i < 4; i++)
#pragma unroll
    for (int j = 0; j < 4; j++) {
      const float4 xv = *(const float4*)(xb + (size_t)(i * 56 + j) * CD);
      const int t = i * 4 + j;
      a0 += xv.x * dw_w[(c4 + 0) * 16 + t];
      a1 += xv.y * dw_w[(c4 + 1) * 16 + t];
      a2 += xv.z * dw_w[(c4 + 2) * 16 + t];
      a3 += xv.w * dw_w[(c4 + 3) * 16 + t];
    }
  *(float4*)(dwc + (size_t)row * CD + c4) = make_float4(a0, a1, a2, a3);
}

// ---------------------------------------------------------------------------
// Kernel 1b: 1x1 conv as MFMA GEMM [6272][320] @ pwb^T -> +bias, LN, GELU,
// all in registers (no LDS, no barriers). Wave = 16 rows x 400 cols
// (25 f32x4 acc). Row stats: per-lane partials over n, then shfl_xor 8/4/2/1
// within the 16-lane quad group (C row = quad*4+r lives on lanes quad*16+*).
// xs bf16 [6272][416], pad cols zeroed. grid 98 (= 6272/64), 4 waves.
// ---------------------------------------------------------------------------
__global__ __launch_bounds__(256) void k_pwln(const float* __restrict__ dwc,
                                              const u16* __restrict__ pwb,
                                              const float* __restrict__ pw_b,
                                              const float* __restrict__ ln_g,
                                              const float* __restrict__ ln_b,
                                              u16* __restrict__ xs) {
  const int tid = threadIdx.x, lane = tid & 63, wv = tid >> 6;
  const int quad = lane >> 4, l15 = lane & 15;
  const int row0 = blockIdx.x * 64 + wv * 16;
  const f32x4 fz = {0.f, 0.f, 0.f, 0.f};

  bf16x8 A[10];
  {
    const float* xr = dwc + (size_t)(row0 + l15) * CD;
#pragma unroll
    for (int ks = 0; ks < 10; ks++) {
      const float4 a = *(const float4*)(xr + ks * 32 + quad * 8);
      const float4 b = *(const float4*)(xr + ks * 32 + quad * 8 + 4);
      A[ks] = pack8(a, b);
    }
  }
  f32x4 acc[25];
#pragma unroll
  for (int n = 0; n < 25; n++) acc[n] = fz;
#pragma unroll 1
  for (int n = 0; n < 25; n++) {
    const u16* wr = pwb + (size_t)(n * 16 + l15) * CD;
#pragma unroll
    for (int ks = 0; ks < 10; ks++) {
      const bf16x8 B = *(const bf16x8*)(wr + ks * 32 + quad * 8);
      acc[n] = __builtin_amdgcn_mfma_f32_16x16x32_bf16(A[ks], B, acc[n], 0, 0, 0);
    }
    const float pb = pw_b[n * 16 + l15];
#pragma unroll
    for (int r = 0; r < 4; r++) acc[n][r] += pb;
  }
  // LN stats per output row (row = quad*4+r)
  float s[4] = {0.f, 0.f, 0.f, 0.f}, ss[4] = {0.f, 0.f, 0.f, 0.f};
#pragma unroll
  for (int n = 0; n < 25; n++)
#pragma unroll
    for (int r = 0; r < 4; r++) {
      s[r] += acc[n][r];
      ss[r] += acc[n][r] * acc[n][r];
    }
#pragma unroll
  for (int r = 0; r < 4; r++) {
#pragma unroll
    for (int off = 8; off > 0; off >>= 1) {
      s[r] += __shfl_xor(s[r], off);
      ss[r] += __shfl_xor(ss[r], off);
    }
  }
  float mu[4], rstd[4];
#pragma unroll
  for (int r = 0; r < 4; r++) {
    mu[r] = s[r] * (1.f / 400.f);
    const float var = ss[r] * (1.f / 400.f) - mu[r] * mu[r];
    rstd[r] = rsqrtf(var + 1e-5f);
  }
#pragma unroll 1
  for (int n = 0; n < 25; n++) {
    const int col = n * 16 + l15;
    const float g = ln_g[col], bb = ln_b[col];
#pragma unroll
    for (int r = 0; r < 4; r++) {
      const float v = (acc[n][r] - mu[r]) * rstd[r] * g + bb;
      const float ge = 0.5f * v * (1.f + erff(v * 0.70710678118654752f));
      xs[(size_t)(row0 + quad * 4 + r) * 416 + col] = f2bf(ge);
    }
  }
#pragma unroll
  for (int r = 0; r < 4; r++)
    xs[(size_t)(row0 + quad * 4 + r) * 416 + 400 + l15] = 0;
}

// ---------------------------------------------------------------------------
// Kernel 2 (MFMA, barrier-free): [6272][416]bf16 @ kvwT^T -> kb [6272][400],
// vt [32][320][224] (v transposed, keys 196..223 left as poison — harmless).
// grid (98, 3): wave = 16 rows, N-chunk = 15 tiles of 16.
// ---------------------------------------------------------------------------
__global__ __launch_bounds__(256) void k_kv(const u16* __restrict__ xs,
                                            const u16* __restrict__ kvwT,
                                            u16* __restrict__ kb,
                                            u16* __restrict__ vt) {
  const int tid = threadIdx.x, lane = tid & 63, wv = tid >> 6;
  const int quad = lane >> 4, l15 = lane & 15;
  const int mt = blockIdx.x * 4 + wv;  // 0..391
  const f32x4 fz = {0.f, 0.f, 0.f, 0.f};

  bf16x8 A[13];
  {
    const u16* xr = xs + (size_t)(mt * 16 + l15) * 416;
#pragma unroll
    for (int ks = 0; ks < 13; ks++)
      A[ks] = *(const bf16x8*)(xr + ks * 32 + quad * 8);
  }
#pragma unroll 1
  for (int n = 0; n < 15; n++) {
    const int nt = blockIdx.y * 15 + n;
    f32x4 acc = fz;
    const u16* wr = kvwT + (size_t)(nt * 16 + l15) * 416;
#pragma unroll
    for (int ks = 0; ks < 13; ks++) {
      const bf16x8 B = *(const bf16x8*)(wr + ks * 32 + quad * 8);
      acc = __builtin_amdgcn_mfma_f32_16x16x32_bf16(A[ks], B, acc, 0, 0, 0);
    }
    const int col = nt * 16 + l15;
    if (col < 400) {
#pragma unroll
      for (int r = 0; r < 4; r++)
        kb[(size_t)(mt * 16 + quad * 4 + r) * 400 + col] = f2bf(acc[r]);
    } else {
      const int vo = col - 400;
#pragma unroll
      for (int r = 0; r < 4; r++) {
        const int row = mt * 16 + quad * 4 + r;
        const int bb = row / 196, key = row - bb * 196;
        vt[((size_t)(bb * 320 + vo)) * 224 + key] = f2bf(acc[r]);
      }
    }
  }
}

// ---------------------------------------------------------------------------
// Kernel 3 (MFMA, LDS-free, barrier-free): qb = x @ q_w  bf16 [100352][400].
// grid 784: 4 waves x 32 rows. A held in regs (x fp32 -> bf16 in-reg).
// ---------------------------------------------------------------------------
__global__ __launch_bounds__(256) void k_q(const float* __restrict__ x,
                                           const u16* __restrict__ qwT,
                                           u16* __restrict__ qb) {
  const int tid = threadIdx.x, lane = tid & 63, wv = tid >> 6;
  const int quad = lane >> 4, l15 = lane & 15;
  const int r0 = (blockIdx.x * 4 + wv) * 32;
  const f32x4 fz = {0.f, 0.f, 0.f, 0.f};

  bf16x8 A[2][10];
#pragma unroll
  for (int t = 0; t < 2; t++) {
    const float* xr = x + (size_t)(r0 + t * 16 + l15) * CD;
#pragma unroll
    for (int ks = 0; ks < 10; ks++) {
      const float4 a = *(const float4*)(xr + ks * 32 + quad * 8);
      const float4 b = *(const float4*)(xr + ks * 32 + quad * 8 + 4);
      A[t][ks] = pack8(a, b);
    }
  }
#pragma unroll 1
  for (int n = 0; n < 25; n++) {
    f32x4 acc[2] = {fz, fz};
    const u16* wr = qwT + (size_t)(n * 16 + l15) * CD;
#pragma unroll
    for (int ks = 0; ks < 10; ks++) {
      const bf16x8 B = *(const bf16x8*)(wr + ks * 32 + quad * 8);
      acc[0] = __builtin_amdgcn_mfma_f32_16x16x32_bf16(A[0][ks], B, acc[0], 0, 0, 0);
      acc[1] = __builtin_amdgcn_mfma_f32_16x16x32_bf16(A[1][ks], B, acc[1], 0, 0, 0);
    }
#pragma unroll
    for (int t = 0; t < 2; t++)
#pragma unroll
      for (int r = 0; r < 4; r++)
        qb[(size_t)(r0 + t * 16 + quad * 4 + r) * CN + n * 16 + l15] =
            f2bf(acc[t][r]);
  }
}

// ---------------------------------------------------------------------------
// Kernel 4: attention. grid (5, 49, 32), 2 barriers total.
// LDS 36624 B (-> 4 blocks/CU): Ks [208][88] (K=80 exact, cols 80..87 + rows
// 196..207 zeroed); P (wave-private [16][232]) overlays dead Ks.
// S-GEMM runs K=96 via 3x mfma16x16x32 with A zeroed for k>=80 (quads 2,3 of
// third tile); B cross-row overread (cols 88..95 -> next row cols 0..7) is
// finite and multiplied by A-zeros.
// Output: bf16 attn-out written IN PLACE into qb (this block's rows, cols
// h*80+0..63). Safe: this block is the sole reader of those (row,col) bytes
// and its last q read precedes the write. k_proj reads it; fp32 out roundtrip
// eliminated.
// ---------------------------------------------------------------------------
__global__ __launch_bounds__(256) void k_attn(u16* __restrict__ qb,
                                              const u16* __restrict__ kb,
                                              const u16* __restrict__ vt) {
  const int h = blockIdx.x, qt = blockIdx.y, b = blockIdx.z;
  const int tid = threadIdx.x, lane = tid & 63, wv = tid >> 6;
  const int quad = lane >> 4, l15 = lane & 15;
  const int q0 = qt * 64, m0 = wv * 16;
  const f32x4 fz = {0.f, 0.f, 0.f, 0.f};

  __shared__ u16 sm[208 * 88 + 8];  // 36624 B
  u16* Ks = sm;
  u16* P = sm + wv * (16 * 232);  // valid only after barrier #2

  // stage K head-slice: [196][80] -> Ks[196][88], cols 80..87 zeroed
  for (int idx = tid; idx < 196 * 11; idx += 256) {
    const int key = idx / 11, g = idx - key * 11;
    if (g < 10)
      *(uint4*)(Ks + key * 88 + g * 8) = *(const uint4*)(
          kb + ((size_t)(b * NKEY + key)) * CN + h * DQ + g * 8);
    else
      *(uint4*)(Ks + key * 88 + 80) = make_uint4(0, 0, 0, 0);
  }
  // zero rows 196..207 + 8-u16 tail guard (keeps the K96 overread finite)
  for (int idx = tid; idx < 12 * 11 + 1; idx += 256) {
    const int rr = idx / 11, g = idx - rr * 11;
    *(uint4*)(Ks + (196 + rr) * 88 + g * 8) = make_uint4(0, 0, 0, 0);
  }
  __syncthreads();  // barrier #1

  // ---- S = q @ K^T  (13 key-tiles; K=80 exact, A zero-padded to 96)
  f32x4 sacc[13];
#pragma unroll
  for (int n = 0; n < 13; n++) sacc[n] = fz;
  {
    const u16* qr = qb + (size_t)(b * NN + q0 + m0 + l15) * CN + h * DQ;
    bf16x8 a[3];
    a[0] = *(const bf16x8*)(qr + quad * 8);
    a[1] = *(const bf16x8*)(qr + 32 + quad * 8);
    if (quad < 2) {
      a[2] = *(const bf16x8*)(qr + 64 + quad * 8);
    } else {
      union { uint4 u; bf16x8 v; } z;
      z.u = make_uint4(0, 0, 0, 0);
      a[2] = z.v;
    }
#pragma unroll
    for (int n = 0; n < 13; n++)
#pragma unroll
      for (int ks = 0; ks < 3; ks++) {
        const bf16x8 B =
            *(const bf16x8*)(Ks + (n * 16 + l15) * 88 + ks * 32 + quad * 8);
        sacc[n] = __builtin_amdgcn_mfma_f32_16x16x32_bf16(a[ks], B, sacc[n], 0, 0, 0);
      }
  }

  // ---- softmax in registers (keys across 13 regs x 16 lanes)
  {
    float mx[4] = {-1e30f, -1e30f, -1e30f, -1e30f};
#pragma unroll
    for (int n = 0; n < 13; n++)
#pragma unroll
      for (int r = 0; r < 4; r++) {
        const float s = (n == 12 && l15 >= 4) ? -1e30f : sacc[n][r] * SCALE_F;
        sacc[n][r] = s;
        mx[r] = fmaxf(mx[r], s);
      }
#pragma unroll
    for (int r = 0; r < 4; r++) {
      mx[r] = fmaxf(mx[r], __shfl_xor(mx[r], 1));
      mx[r] = fmaxf(mx[r], __shfl_xor(mx[r], 2));
      mx[r] = fmaxf(mx[r], __shfl_xor(mx[r], 4));
      mx[r] = fmaxf(mx[r], __shfl_xor(mx[r], 8));
    }
    float sum[4] = {0.f, 0.f, 0.f, 0.f};
#pragma unroll
    for (int n = 0; n < 13; n++)
#pragma unroll
      for (int r = 0; r < 4; r++) {
        const float e = __expf(sacc[n][r] - mx[r]);
        sacc[n][r] = e;
        sum[r] += e;
      }
#pragma unroll
    for (int r = 0; r < 4; r++) {
      sum[r] += __shfl_xor(sum[r], 1);
      sum[r] += __shfl_xor(sum[r], 2);
      sum[r] += __shfl_xor(sum[r], 4);
      sum[r] += __shfl_xor(sum[r], 8);
    }
#pragma unroll
    for (int r = 0; r < 4; r++) {
      const float inv = 1.f / sum[r];
#pragma unroll
      for (int n = 0; n < 13; n++) sacc[n][r] *= inv;
    }
  }
  __syncthreads();  // barrier #2: Ks dead, P region live

  // ---- P -> wave-private LDS [16][232] (cols 196..223 zeroed)
  {
    const int zr = lane >> 2, zc0 = 196 + (lane & 3) * 7;
#pragma unroll
    for (int t = 0; t < 7; t++) P[zr * 232 + zc0 + t] = 0;
#pragma unroll
    for (int n = 0; n < 13; n++) {
      if (n == 12 && l15 >= 4) continue;
#pragma unroll
      for (int r = 0; r < 4; r++)
        P[(quad * 4 + r) * 232 + n * 16 + l15] = f2bf(sacc[n][r]);
    }
  }

  // ---- O = P @ V   (V B-frags direct from global vt [b*320+vo][224])
  f32x4 oacc[4];
#pragma unroll
  for (int n = 0; n < 4; n++) oacc[n] = fz;
  {
    const u16* vbase = vt + (size_t)(b * 320 + h * DV) * 224;
#pragma unroll
    for (int kk = 0; kk < 7; kk++) {
      const bf16x8 a = *(const bf16x8*)(P + l15 * 232 + kk * 32 + quad * 8);
#pragma unroll
      for (int n = 0; n < 4; n++) {
        const bf16x8 B = *(const bf16x8*)(vbase + (size_t)(n * 16 + l15) * 224 +
                                          kk * 32 + quad * 8);
        oacc[n] = __builtin_amdgcn_mfma_f32_16x16x32_bf16(a, B, oacc[n], 0, 0, 0);
      }
    }
  }
  // ---- bf16 attn-out overlay into qb (own rows, cols h*80+0..63)
#pragma unroll
  for (int n = 0; n < 4; n++)
#pragma unroll
    for (int r = 0; r < 4; r++)
      qb[(size_t)(b * NN + q0 + m0 + quad * 4 + r) * CN + h * DQ + n * 16 +
         l15] = f2bf(oacc[n][r]);
}

// ---------------------------------------------------------------------------
// Kernel 5 (LDS-free, barrier-free): out = ao @ proj_w + proj_b.
// ao = bf16 attn-out overlaid in qb: row stride 400, head h at cols h*80+0..63.
// A-frag col c = ks*32+quad*8+i  ->  addr row*400 + (ks>>1)*80 + (ks&1)*32 + quad*8.
// grid 784: wave = 32 rows. No pack needed (A already bf16).
// ---------------------------------------------------------------------------
__global__ __launch_bounds__(256) void k_proj(const u16* __restrict__ ao,
                                              const u16* __restrict__ pwT,
                                              const float* __restrict__ proj_b,
                                              float* __restrict__ out) {
  const int tid = threadIdx.x, lane = tid & 63, wv = tid >> 6;
  const int quad = lane >> 4, l15 = lane & 15;
  const int r0 = (blockIdx.x * 4 + wv) * 32;
  const f32x4 fz = {0.f, 0.f, 0.f, 0.f};

  bf16x8 A[2][10];
#pragma unroll
  for (int t = 0; t < 2; t++) {
    const u16* xr = ao + (size_t)(r0 + t * 16 + l15) * CN;
#pragma unroll
    for (int ks = 0; ks < 10; ks++)
      A[t][ks] = *(const bf16x8*)(xr + (ks >> 1) * DQ + (ks & 1) * 32 + quad * 8);
  }
#pragma unroll 1
  for (int n = 0; n < 20; n++) {
    f32x4 acc[2] = {fz, fz};
    const u16* wr = pwT + (size_t)(n * 16 + l15) * CD;
#pragma unroll
    for (int ks = 0; ks < 10; ks++) {
      const bf16x8 B = *(const bf16x8*)(wr + ks * 32 + quad * 8);
      acc[0] = __builtin_amdgcn_mfma_f32_16x16x32_bf16(A[0][ks], B, acc[0], 0, 0, 0);
      acc[1] = __builtin_amdgcn_mfma_f32_16x16x32_bf16(A[1][ks], B, acc[1], 0, 0, 0);
    }
    const float pb = proj_b[n * 16 + l15];
#pragma unroll
    for (int t = 0; t < 2; t++)
#pragma unroll
      for (int r = 0; r < 4; r++)
        out[(size_t)(r0 + t * 16 + quad * 4 + r) * CD + n * 16 + l15] =
            acc[t][r] + pb;
  }
}

// ---------------------------------------------------------------------------
extern "C" void kernel_launch(void* const* d_in, const int* in_sizes, int n_in,
                              void* d_out, int out_size, void* d_ws,
                              size_t ws_size, hipStream_t stream) {
  const float* x = (const float*)d_in[0];
  const float* dw_w = (const float*)d_in[3];
  const float* dw_b = (const float*)d_in[4];
  const float* pw_w = (const float*)d_in[5];
  const float* pw_b = (const float*)d_in[6];
  const float* ln_g = (const float*)d_in[7];
  const float* ln_b = (const float*)d_in[8];
  const float* q_w = (const float*)d_in[9];
  const float* k_w = (const float*)d_in[10];
  const float* v_w = (const float*)d_in[11];
  const float* proj_w = (const float*)d_in[12];
  const float* proj_b = (const float*)d_in[13];
  float* out = (float*)d_out;

  u16* w = (u16*)d_ws;
  u16* xs16 = w;                    // [6272][416]       = 2,609,152
  u16* kb16 = xs16 + 2609152;       // [6272][400]       = 2,508,800
  u16* vt16 = kb16 + 2508800;       // [32*320][224]     = 2,293,760
  u16* qb16 = vt16 + 2293760;       // [100352][400]+64  = 40,140,864 (ao overlay)
  u16* qwT = qb16 + 40140864;       // [400][320]        = 128,000
  u16* pwT = qwT + 128000;          // [320][320]        = 102,400
  u16* kvwT = pwT + 102400;         // [720][416]        = 299,520
                                    // total 96.2 MB
  // transient overlays inside the qb region (dead before k_q writes qb):
  float* dwc = (float*)qb16;        // fp32 [6272][320]  = 8,028,160 B
  u16* pwb = qb16 + 4100000;        // bf16 [400][320]   = 256,000 B

  k_prep<<<512, 256, 0, stream>>>(q_w, proj_w, k_w, v_w, pw_w, qwT, pwT, kvwT,
                                  pwb);
  k_dw<<<1960, 256, 0, stream>>>(x, dw_w, dw_b, dwc);
  k_pwln<<<98, 256, 0, stream>>>(dwc, pwb, pw_b, ln_g, ln_b, xs16);
  k_kv<<<dim3(98, 3), 256, 0, stream>>>(xs16, kvwT, kb16, vt16);
  k_q<<<784, 256, 0, stream>>>(x, qwT, qb16);
  k_attn<<<dim3(NH, 49, NB), 256, 0, stream>>>(qb16, kb16, vt16);
  k_proj<<<784, 256, 0, stream>>>(qb16, pwT, proj_b, out);
}